// Round 1
// baseline (82.498 us; speedup 1.0000x reference)
//
#include <hip/hip_runtime.h>
#include <math.h>

// GMMflow_fast: B=2048, M=1024, D=64.  R12: gload_lds staging + pre-swizzled
// global buffers (from R11 = R8 best, 82.4 us).
//   prep (384 blocks): blocks 0-255: a=1/Sigma, p'=-2*mut*a (bf16 hi/lo,
//     XOR-swizzled), VT=[K|g] bf16 (swizzled per 64-m chunk), q[m] f32.
//     blocks 256-383: A1=[x^2|x] hi/lo bf16 from X, XOR-swizzled (moved out
//     of main: was recomputed 16x, ~400 VALU/wave of bf16rn per split).
//   main (grid 32x16, 2 blk/CU): stage A1h/A1l/B1h/B1l via 16 linear
//     global_load_lds dwordx4 (no VALU, no reg round-trip); GEMM1 3-pass
//     bf16 hi/lo K=128 with swizzled ds_read_b128 (bank-uniform); V gload_lds
//     issued BEFORE W-phase exp/shfl (latency hidden); w=exp(clip)*Lam, norm
//     via shfl of bf16-rounded w; GEMM2 single bf16 K=64.  Partials S1|S2 bf16.
//   finalize (256 blocks x 128): reduce 16 splits, u=(x*S1+S2)/n.
// Arithmetic path identical to R11 (same bf16rn of same f32 values) ->
// absmax should be unchanged.
// Falsified variants (record): R6 fused-tail (+41); R7 inline prep (+13);
// R9 spin grid-barrier (+170); R10 direct-global MFMA frags (+1.9).

#define B_N 2048
#define M_N 1024
#define NSPLIT 16
#define BT 64
#define MS 64

typedef short bf16x8 __attribute__((ext_vector_type(8)));
typedef float f32x4 __attribute__((ext_vector_type(4)));

static __device__ __forceinline__ unsigned short bf16rn(float f) {
    union { float f; unsigned u; } v; v.f = f;
    unsigned r = v.u + 0x7FFF + ((v.u >> 16) & 1);
    return (unsigned short)(r >> 16);
}
static __device__ __forceinline__ float bf2f(unsigned short h) {
    union { unsigned u; float f; } v; v.u = ((unsigned)h) << 16;
    return v.f;
}
static __device__ __forceinline__ void st4(unsigned short* p, unsigned short a,
                                           unsigned short b, unsigned short c, unsigned short d) {
    union { unsigned short u[4]; float2 f; } t;
    t.u[0] = a; t.u[1] = b; t.u[2] = c; t.u[3] = d;
    *(float2*)p = t.f;
}
static __device__ __forceinline__ void gload16(const void* g, void* l) {
    __builtin_amdgcn_global_load_lds(
        (const __attribute__((address_space(1))) unsigned int*)g,
        (__attribute__((address_space(3))) unsigned int*)l, 16, 0, 0);
}

// ---------------- prep: 384 blocks ----------------
// blocks [0,256): 4 m each -> B1 (swizzled), VT (swizzled), qArr
// blocks [256,384): 16 b each -> A1 = [x^2|x] hi/lo (swizzled)
__global__ __launch_bounds__(256)
void prep_kernel(const float* __restrict__ X,
                 const float* __restrict__ Mu0, const float* __restrict__ Mu1,
                 const float* __restrict__ S0, const float* __restrict__ S1,
                 const float* __restrict__ T, const float* __restrict__ E,
                 unsigned short* __restrict__ B1h, unsigned short* __restrict__ B1l,
                 unsigned short* __restrict__ A1h, unsigned short* __restrict__ A1l,
                 unsigned short* __restrict__ VTh, float* __restrict__ qArr) {
    const int tid = threadIdx.x;
    if (blockIdx.x >= 256) {
        // ---- A-prep: row b = global batch index ----
        const int b = (blockIdx.x - 256) * 16 + (tid >> 4);
        const int d0 = (tid & 15) * 4;
        float4 xv = ((const float4*)X)[(size_t)b * 16 + (tid & 15)];
        float xs[4] = {xv.x, xv.y, xv.z, xv.w};
        unsigned short yh[4], yl[4], xh[4], xl[4];
        #pragma unroll
        for (int k = 0; k < 4; k++) {
            float y = xs[k] * xs[k];
            yh[k] = bf16rn(y);     yl[k] = bf16rn(y - bf2f(yh[k]));
            xh[k] = bf16rn(xs[k]); xl[k] = bf16rn(xs[k] - bf2f(xh[k]));
        }
        const int dp = d0 ^ ((b & 7) << 3);    // XOR swizzle, 8-short aligned
        const int base = b * 128;
        st4(A1h + base + dp,      yh[0], yh[1], yh[2], yh[3]);
        st4(A1l + base + dp,      yl[0], yl[1], yl[2], yl[3]);
        st4(A1h + base + 64 + dp, xh[0], xh[1], xh[2], xh[3]);
        st4(A1l + base + 64 + dp, xl[0], xl[1], xl[2], xl[3]);
        return;
    }
    __shared__ float sK[4 * 65];
    __shared__ float sG[4 * 65];
    const int m0 = blockIdx.x * 4;
    const int mi = tid >> 6, d = tid & 63;
    const int m = m0 + mi;
    const float t = T[0], e = E[0];
    const float eps2 = e * e, eps4 = eps2 * eps2, omt = 1.f - t;
    int idx = m * 64 + d;
    float s0 = S0[idx], s1 = S1[idx];
    float mu0 = Mu0[idx], mu1 = Mu1[idx];
    float Ds = sqrtf(4.f * s0 * s1 + eps4);
    float Cs = 0.5f * (Ds - eps2);
    float sig = omt * omt * s0 + t * t * s1 + 2.f * t * omt * (Cs + 0.5f * eps2);
    float St = (t * s1 + omt * Cs) - (omt * s0 + t * Cs) - eps2 * t;
    float a = 1.f / sig;
    float K = St * a;
    float mut = omt * mu0 + t * mu1;
    float pp = -2.f * mut * a;
    float g = (mu1 - mu0) - K * mut;
    const int dp = d ^ ((m & 7) << 3);         // XOR swizzle
    unsigned short ah = bf16rn(a);
    B1h[m * 128 + dp] = ah;
    B1l[m * 128 + dp] = bf16rn(a - bf2f(ah));
    unsigned short ph = bf16rn(pp);
    B1h[m * 128 + 64 + dp] = ph;
    B1l[m * 128 + 64 + dp] = bf16rn(pp - bf2f(ph));
    sK[mi * 65 + d] = K;
    sG[mi * 65 + d] = g;
    float qd = mut * mut * a + __logf(sig);
    #pragma unroll
    for (int off = 32; off > 0; off >>= 1) qd += __shfl_xor(qd, off, 64);
    if (d == 0) qArr[m] = qd;
    __syncthreads();
    // VT[n][m] transpose write, swizzled within each 64-m chunk
    #pragma unroll
    for (int it = 0; it < 2; it++) {
        int i = it * 256 + tid;
        int n = i >> 2, mm = i & 3;
        float v = (n < 64) ? sK[mm * 65 + n] : sG[mm * 65 + (n - 64)];
        int mg = m0 + mm;
        VTh[n * M_N + (mg & ~63) + ((mg & 63) ^ ((n & 7) << 3))] = bf16rn(v);
    }
}

// ---------------- main: grid (32,16), 256 thr, 66 KB LDS, 2 blocks/CU ----------------
// LDS map: [0,16K) A1h | [16K,32K) A1l | [32K,48K) B1h | [48K,64K) B1l
//          | 64K sQ(256B) sL(256B).   Post-GEMM1 overlay: [0,16K) V, [16K,24K) W.
__global__ __launch_bounds__(256, 2)
void gmm_main_kernel(const float* __restrict__ Lam,
                     const unsigned short* __restrict__ B1h, const unsigned short* __restrict__ B1l,
                     const unsigned short* __restrict__ A1h, const unsigned short* __restrict__ A1l,
                     const unsigned short* __restrict__ VTh,
                     const float* __restrict__ qArr,
                     unsigned short* __restrict__ partBF, float* __restrict__ partN) {
    __shared__ __align__(16) char smem_raw[66048];
    const unsigned short* smA1h = (const unsigned short*)smem_raw;
    const unsigned short* smA1l = (const unsigned short*)(smem_raw + 16384);
    const unsigned short* smB1h = (const unsigned short*)(smem_raw + 32768);
    const unsigned short* smB1l = (const unsigned short*)(smem_raw + 49152);
    const unsigned short* sV = (const unsigned short*)smem_raw;          // overlay
    unsigned short* sW = (unsigned short*)(smem_raw + 16384);            // overlay
    float* sQ = (float*)(smem_raw + 65536);
    float* sL = (float*)(smem_raw + 65792);

    const int tid  = threadIdx.x;
    const int Boff = blockIdx.x * BT;
    const int Moff = blockIdx.y * MS;
    const int w    = tid >> 6;
    const int lane = tid & 63;
    const int c = lane & 15, q = lane >> 4;
    const int wb = w >> 1;     // b-half
    const int wm = w & 1;      // GEMM1 m-half / GEMM2 n-half
    const int swz = (c & 7) << 3;   // fragment-read swizzle (row&7 == c&7 everywhere)

    // ---- stage A1/B1 tiles via linear global_load_lds (buffers pre-swizzled) ----
    {
        const char* gA1h = (const char*)A1h + (size_t)Boff * 256;
        const char* gA1l = (const char*)A1l + (size_t)Boff * 256;
        const char* gB1h = (const char*)B1h + (size_t)Moff * 256;
        const char* gB1l = (const char*)B1l + (size_t)Moff * 256;
        const int off = tid * 16;
        #pragma unroll
        for (int cc = 0; cc < 4; cc++) {
            gload16(gA1h + cc * 4096 + off, smem_raw +         cc * 4096 + off);
            gload16(gA1l + cc * 4096 + off, smem_raw + 16384 + cc * 4096 + off);
            gload16(gB1h + cc * 4096 + off, smem_raw + 32768 + cc * 4096 + off);
            gload16(gB1l + cc * 4096 + off, smem_raw + 49152 + cc * 4096 + off);
        }
        if (tid < 64) sQ[tid] = qArr[Moff + tid];
        else if (tid < 128) sL[tid - 64] = Lam[Moff + tid - 64];
    }
    __syncthreads();

    // ---- GEMM1: wave quadrant 32b x 32m, K=128, 3 hi/lo passes ----
    f32x4 acc1[2][2];
    #pragma unroll
    for (int i = 0; i < 2; i++)
        #pragma unroll
        for (int j = 0; j < 2; j++) acc1[i][j] = (f32x4){0.f, 0.f, 0.f, 0.f};
    #pragma unroll
    for (int ks = 0; ks < 4; ks++) {
        const int p = (ks * 32 + q * 8) ^ swz;
        bf16x8 Ah[2], Al[2], Bh[2], Bl[2];
        #pragma unroll
        for (int i = 0; i < 2; i++) {
            int row = wb * 32 + i * 16 + c;
            Ah[i] = *(const bf16x8*)(smA1h + row * 128 + p);
            Al[i] = *(const bf16x8*)(smA1l + row * 128 + p);
        }
        #pragma unroll
        for (int j = 0; j < 2; j++) {
            int row = wm * 32 + j * 16 + c;
            Bh[j] = *(const bf16x8*)(smB1h + row * 128 + p);
            Bl[j] = *(const bf16x8*)(smB1l + row * 128 + p);
        }
        #pragma unroll
        for (int i = 0; i < 2; i++)
            #pragma unroll
            for (int j = 0; j < 2; j++) {
                acc1[i][j] = __builtin_amdgcn_mfma_f32_16x16x32_bf16(Ah[i], Bh[j], acc1[i][j], 0, 0, 0);
                acc1[i][j] = __builtin_amdgcn_mfma_f32_16x16x32_bf16(Ah[i], Bl[j], acc1[i][j], 0, 0, 0);
                acc1[i][j] = __builtin_amdgcn_mfma_f32_16x16x32_bf16(Al[i], Bh[j], acc1[i][j], 0, 0, 0);
            }
    }
    __syncthreads();   // A/B regions dead -> overlays

    // ---- issue V gload_lds FIRST (latency hides under W compute), then W ----
    {
        const int off = tid * 16;
        const char* gV = (const char*)VTh;
        #pragma unroll
        for (int cc = 0; cc < 4; cc++) {
            int db = cc * 4096 + off;            // dest byte in V region [0,16K)
            // LDS row n = db>>7 (128B rows), col byte = db&127; global row stride 2048B
            gload16(gV + (size_t)(db >> 7) * 2048 + Moff * 2 + (db & 127), smem_raw + db);
        }
        float nsum[2][4];
        #pragma unroll
        for (int i = 0; i < 2; i++)
            #pragma unroll
            for (int r = 0; r < 4; r++) nsum[i][r] = 0.f;
        #pragma unroll
        for (int i = 0; i < 2; i++)
            #pragma unroll
            for (int j = 0; j < 2; j++) {
                int m = wm * 32 + j * 16 + c;
                float qm = sQ[m], lm = sL[m];
                #pragma unroll
                for (int r = 0; r < 4; r++) {
                    int bl = wb * 32 + i * 16 + q * 4 + r;
                    float lw = -0.5f * (acc1[i][j][r] + qm);
                    lw = fminf(50.f, fmaxf(-50.f, lw));
                    float wf = __expf(lw) * lm;
                    unsigned short wh = bf16rn(wf);
                    sW[bl * 64 + (m ^ ((bl & 7) << 3))] = wh;
                    nsum[i][r] += bf2f(wh);
                }
            }
        #pragma unroll
        for (int mask = 1; mask <= 8; mask <<= 1)
            #pragma unroll
            for (int i = 0; i < 2; i++)
                #pragma unroll
                for (int r = 0; r < 4; r++)
                    nsum[i][r] += __shfl_xor(nsum[i][r], mask, 64);
        if (c == 0) {
            #pragma unroll
            for (int i = 0; i < 2; i++)
                #pragma unroll
                for (int r = 0; r < 4; r++) {
                    int b = Boff + wb * 32 + i * 16 + q * 4 + r;
                    partN[((size_t)blockIdx.y * B_N + b) * 2 + wm] = nsum[i][r];
                }
        }
    }
    __syncthreads();   // drains V gloads + sW writes

    // ---- GEMM2: wave 32b x 64n, K=64, single pass ----
    f32x4 acc2[2][4];
    #pragma unroll
    for (int i = 0; i < 2; i++)
        #pragma unroll
        for (int j = 0; j < 4; j++) acc2[i][j] = (f32x4){0.f, 0.f, 0.f, 0.f};
    #pragma unroll
    for (int ks = 0; ks < 2; ks++) {
        const int p = (ks * 32 + q * 8) ^ swz;
        bf16x8 Wf[2], Vf[4];
        #pragma unroll
        for (int i = 0; i < 2; i++) {
            int row = wb * 32 + i * 16 + c;
            Wf[i] = *(const bf16x8*)(sW + row * 64 + p);
        }
        #pragma unroll
        for (int j = 0; j < 4; j++) {
            int row = wm * 64 + j * 16 + c;
            Vf[j] = *(const bf16x8*)(sV + row * 64 + p);
        }
        #pragma unroll
        for (int i = 0; i < 2; i++)
            #pragma unroll
            for (int j = 0; j < 4; j++)
                acc2[i][j] = __builtin_amdgcn_mfma_f32_16x16x32_bf16(Wf[i], Vf[j], acc2[i][j], 0, 0, 0);
    }

    // ---- partial S1|S2 writes (bf16) ----
    #pragma unroll
    for (int i = 0; i < 2; i++)
        #pragma unroll
        for (int j = 0; j < 4; j++) {
            #pragma unroll
            for (int r = 0; r < 4; r++) {
                int b = Boff + wb * 32 + i * 16 + q * 4 + r;
                int n = wm * 64 + j * 16 + c;
                partBF[((size_t)blockIdx.y * B_N + b) * 128 + n] = bf16rn(acc2[i][j][r]);
            }
        }
}

// ---------------- finalize: 256 blocks x 128, thread per (b, d-quad) ----------------
__global__ __launch_bounds__(128)
void finalize_kernel(const float* __restrict__ X, const unsigned short* __restrict__ partBF,
                     const float* __restrict__ partN, float* __restrict__ out) {
    int gid = blockIdx.x * 128 + threadIdx.x;   // 32768 = 2048 b x 16 quads
    int b = gid >> 4, d0 = (gid & 15) * 4;
    float a1[4] = {0.f, 0.f, 0.f, 0.f}, a2[4] = {0.f, 0.f, 0.f, 0.f}, nn = 0.f;
    #pragma unroll
    for (int s = 0; s < NSPLIT; s++) {
        const unsigned short* row = partBF + ((size_t)s * B_N + b) * 128;
        ushort4 v1 = *(const ushort4*)(row + d0);
        ushort4 v2 = *(const ushort4*)(row + 64 + d0);
        a1[0] += bf2f(v1.x); a1[1] += bf2f(v1.y); a1[2] += bf2f(v1.z); a1[3] += bf2f(v1.w);
        a2[0] += bf2f(v2.x); a2[1] += bf2f(v2.y); a2[2] += bf2f(v2.z); a2[3] += bf2f(v2.w);
        float2 nv = *(const float2*)(partN + ((size_t)s * B_N + b) * 2);
        nn += nv.x + nv.y;
    }
    float rn = 1.f / nn;
    float4 xv = *(const float4*)(X + (size_t)b * 64 + d0);
    float4 o;
    o.x = (xv.x * a1[0] + a2[0]) * rn;
    o.y = (xv.y * a1[1] + a2[1]) * rn;
    o.z = (xv.z * a1[2] + a2[2]) * rn;
    o.w = (xv.w * a1[3] + a2[3]) * rn;
    *(float4*)(out + (size_t)b * 64 + d0) = o;
}

extern "C" void kernel_launch(void* const* d_in, const int* in_sizes, int n_in,
                              void* d_out, int out_size, void* d_ws, size_t ws_size,
                              hipStream_t stream) {
    (void)in_sizes; (void)n_in; (void)out_size; (void)ws_size;
    const float* X   = (const float*)d_in[0];
    const float* Mu0 = (const float*)d_in[1];
    const float* Mu1 = (const float*)d_in[2];
    const float* S0  = (const float*)d_in[3];
    const float* S1  = (const float*)d_in[4];
    const float* Lam = (const float*)d_in[5];
    const float* T   = (const float*)d_in[6];
    const float* E   = (const float*)d_in[7];

    char* ws = (char*)d_ws;
    unsigned short* A1h   = (unsigned short*)(ws);                    // 512 KB
    unsigned short* A1l   = (unsigned short*)(ws + 524288);           // 512 KB
    unsigned short* B1h   = (unsigned short*)(ws + 1048576);          // 256 KB
    unsigned short* B1l   = (unsigned short*)(ws + 1310720);          // 256 KB
    unsigned short* VTh   = (unsigned short*)(ws + 1572864);          // 256 KB
    float*          qArr  = (float*)(ws + 1835008);                   // 4 KB
    unsigned short* partBF= (unsigned short*)(ws + 1839104);          // 8.39 MB
    float*          partN = (float*)(ws + 1839104 + 8388608);         // 512 KB

    prep_kernel<<<384, 256, 0, stream>>>(X, Mu0, Mu1, S0, S1, T, E,
                                         B1h, B1l, A1h, A1l, VTh, qArr);
    dim3 grid(B_N / BT, NSPLIT);
    gmm_main_kernel<<<grid, 256, 0, stream>>>(Lam, B1h, B1l, A1h, A1l, VTh, qArr,
                                              partBF, partN);
    finalize_kernel<<<256, 128, 0, stream>>>(X, partBF, partN, (float*)d_out);
}